// Round 10
// baseline (78.994 us; speedup 1.0000x reference)
//
#include <hip/hip_runtime.h>

typedef __attribute__((ext_vector_type(8))) short bf16x8;   // 8 bf16 (4 VGPRs)
typedef __attribute__((ext_vector_type(4))) float f32x4;

__device__ inline unsigned short f2bf(float f) {
  unsigned int u = __builtin_bit_cast(unsigned int, f);
  u += 0x7fffu + ((u >> 16) & 1u);     // round-to-nearest-even
  return (unsigned short)(u >> 16);
}

// C (512x256): plain row-major bf16 copy + exact fp32 csq. One wave per row.
__global__ void prep_c(const float* __restrict__ C, unsigned short* __restrict__ Cbf,
                       float* __restrict__ csq, int K) {
  const int w = threadIdx.x >> 6, lane = threadIdx.x & 63;
  const int row = blockIdx.x * 4 + w;
  if (row >= K) return;
  const float4 v = *reinterpret_cast<const float4*>(&C[(size_t)row * 256 + lane * 4]);
  ushort4 b;
  b.x = f2bf(v.x); b.y = f2bf(v.y); b.z = f2bf(v.z); b.w = f2bf(v.w);
  *reinterpret_cast<ushort4*>(&Cbf[(size_t)row * 256 + lane * 4]) = b;
  float sq = v.x * v.x + v.y * v.y + v.z * v.z + v.w * v.w;
#pragma unroll
  for (int o = 32; o; o >>= 1) sq += __shfl_xor(sq, o);
  if (lane == 0) csq[row] = sq;
}

// Fused: out[m][n] = ||F_m||^2 + ||C_n||^2 - 2*F_m.C_n
// ZERO barriers, zero staging LDS. Wave owns 16 F-rows (A direct to regs,
// r9-proven). B fragments loaded per-lane DIRECT from L2-resident Cbf (the
// 4 kh-lanes of one instruction cover a full 64B line per center row).
// Output recoalesced through a tiny wave-private LDS buffer (272B padded
// rows, conflict-free) -> 256B-contiguous store segments (full 128B lines).
// Swapped MFMA operands [verified r7-r9]. 512 blocks, no sync anywhere.
__global__ __launch_bounds__(256, 3) void dist_fused(
    const float* __restrict__ F, const unsigned short* __restrict__ Cbf,
    const float* __restrict__ csq, float* __restrict__ out, int M, int N) {
  __shared__ __align__(16) char stg[4][16 * 272];   // 17 KB total, wave-private slabs

  const int t = threadIdx.x;
  const int w = t >> 6, l = t & 63;
  const int rl = l & 15, kh = l >> 4;
  const int m0 = blockIdx.x * 64;
  const int mrow = m0 + w * 16 + rl;

  // ---- A: 16 independent HBM loads straight to registers (no LDS, no wait
  // until first use). Lane (rl,kh) covers floats k = kt*32+kh*8 .. +7.
  const char* Arow = (const char*)F + (size_t)mrow * 1024 + kh * 32;
  f32x4 a0[8], a1[8];
#pragma unroll
  for (int kt = 0; kt < 8; ++kt) {
    a0[kt] = *reinterpret_cast<const f32x4*>(Arow + kt * 128);
    a1[kt] = *reinterpret_cast<const f32x4*>(Arow + kt * 128 + 16);
  }

  // fp32->bf16 fragments + exact row-norm partial (this lane's 64 elements).
  bf16x8 af[8];
  float rsq = 0.f;
#pragma unroll
  for (int kt = 0; kt < 8; ++kt) {
    const f32x4 x = a0[kt], y = a1[kt];
    rsq += x[0] * x[0] + x[1] * x[1] + x[2] * x[2] + x[3] * x[3] +
           y[0] * y[0] + y[1] * y[1] + y[2] * y[2] + y[3] * y[3];
    bf16x8 v;
    v[0] = (short)f2bf(x[0]); v[1] = (short)f2bf(x[1]);
    v[2] = (short)f2bf(x[2]); v[3] = (short)f2bf(x[3]);
    v[4] = (short)f2bf(y[0]); v[5] = (short)f2bf(y[1]);
    v[6] = (short)f2bf(y[2]); v[7] = (short)f2bf(y[3]);
    af[kt] = v;
  }
  // Sum the 4 kh-slices -> every lane holds its F-row's full squared norm.
  float fv = rsq;
  fv += __shfl_xor(fv, 16);
  fv += __shfl_xor(fv, 32);

  // Per-lane B base: center row (ni*16 + rl), k-slice byte kh*16.
  const char* Bbase = (const char*)Cbf + (size_t)rl * 512 + kh * 16;
  char* sw = stg[w];   // this wave's 16x272B staging slab

  for (int ng = 0; ng < 8; ++ng) {   // 8 groups of 64 centers
    f32x4 acc[4];
#pragma unroll
    for (int nig = 0; nig < 4; ++nig) acc[nig] = (f32x4){0.f, 0.f, 0.f, 0.f};

#pragma unroll
    for (int nig = 0; nig < 4; ++nig) {
      const char* bp = Bbase + (size_t)(ng * 4 + nig) * 8192;   // 16 rows * 512B
#pragma unroll
      for (int kt = 0; kt < 8; ++kt) {
        const bf16x8 bfr = *reinterpret_cast<const bf16x8*>(bp + kt * 64);
        // SWAPPED: D col = F-row (rl), D row = center (kh*4+reg). [r7-r9]
        acc[nig] = __builtin_amdgcn_mfma_f32_16x16x32_bf16(bfr, af[kt], acc[nig], 0, 0, 0);
      }
    }

    // Combine + stage to wave-private LDS in n-linear order.
    // Write addr = rl*272 + nig*64 + kh*16: bank-quad = (rl+nig*4+kh)&7,
    // uniform 8 lanes/quad -> conflict-free.
#pragma unroll
    for (int nig = 0; nig < 4; ++nig) {
      const int n = ng * 64 + nig * 16 + kh * 4;
      const float4 cs4 = *reinterpret_cast<const float4*>(&csq[n]);
      float4 v;
      v.x = fv + cs4.x - 2.0f * acc[nig][0];
      v.y = fv + cs4.y - 2.0f * acc[nig][1];
      v.z = fv + cs4.z - 2.0f * acc[nig][2];
      v.w = fv + cs4.w - 2.0f * acc[nig][3];
      *reinterpret_cast<float4*>(sw + rl * 272 + nig * 64 + kh * 16) = v;
    }

    // Flush coalesced: per pass, 4 rows x 256B-contiguous segments (full
    // 128B lines, no write amplification). Wave-private -> no barrier;
    // compiler inserts the lgkmcnt for the same-wave LDS dependency.
#pragma unroll
    for (int p = 0; p < 4; ++p) {
      const int r16 = p * 4 + kh;
      const float4 v = *reinterpret_cast<const float4*>(sw + r16 * 272 + rl * 16);
      *reinterpret_cast<float4*>(
          &out[(size_t)(m0 + w * 16 + r16) * N + ng * 64 + rl * 4]) = v;
    }
  }
}

extern "C" void kernel_launch(void* const* d_in, const int* in_sizes, int n_in,
                              void* d_out, int out_size, void* d_ws, size_t ws_size,
                              hipStream_t stream) {
  const float* F = (const float*)d_in[0];   // (16, 2048, 256) fp32
  const float* C = (const float*)d_in[1];   // (1, 512, 256) fp32
  float* out = (float*)d_out;               // (16, 2048, 512) fp32
  const int D = 256;
  const int M = in_sizes[0] / D;            // 32768
  const int N = in_sizes[1] / D;            // 512

  unsigned short* Cbf = (unsigned short*)d_ws;    // N*256 bf16 row-major
  float* csq = (float*)(Cbf + (size_t)N * D);     // N fp32

  hipLaunchKernelGGL(prep_c, dim3(N / 4), dim3(256), 0, stream, C, Cbf, csq, N);
  hipLaunchKernelGGL(dist_fused, dim3(M / 64), dim3(256), 0, stream,
                     F, Cbf, csq, out, M, N);
}

// Round 11
// 34.049 us; speedup vs baseline: 2.3200x; 2.3200x over previous
//
#include <hip/hip_runtime.h>

typedef __attribute__((ext_vector_type(8))) short bf16x8;   // 8 bf16 (4 VGPRs)
typedef __attribute__((ext_vector_type(4))) float f32x4;

#define NCH 8       // chunks of 32 centers over this block's 256-center half

__device__ inline unsigned short f2bf(float f) {
  unsigned int u = __builtin_bit_cast(unsigned int, f);
  u += 0x7fffu + ((u >> 16) & 1u);     // round-to-nearest-even
  return (unsigned short)(u >> 16);
}

__device__ inline void gload16(const void* g, void* l) {
  __builtin_amdgcn_global_load_lds(
      (const __attribute__((address_space(1))) void*)g,
      (__attribute__((address_space(3))) void*)l, 16, 0, 0);
}

// C (512x256): bf16 copy pre-XOR-swizzled within each 128B sub-block of the
// 512B row (byte ^= (row&7)<<4) + exact fp32 csq. One wave per row. [r9-proven]
__global__ void prep_c(const float* __restrict__ C, unsigned short* __restrict__ Cbf,
                       float* __restrict__ csq, int K) {
  const int w = threadIdx.x >> 6, lane = threadIdx.x & 63;
  const int row = blockIdx.x * 4 + w;
  if (row >= K) return;
  const float4 v = *reinterpret_cast<const float4*>(&C[(size_t)row * 256 + lane * 4]);
  ushort4 b;
  b.x = f2bf(v.x); b.y = f2bf(v.y); b.z = f2bf(v.z); b.w = f2bf(v.w);
  const int boff = (lane * 8) ^ ((row & 7) << 4);
  *reinterpret_cast<ushort4*>((char*)Cbf + (size_t)row * 512 + boff) = b;
  float sq = v.x * v.x + v.y * v.y + v.z * v.z + v.w * v.w;
#pragma unroll
  for (int o = 32; o; o >>= 1) sq += __shfl_xor(sq, o);
  if (lane == 0) csq[row] = sq;
}

// Fused: out[m][n] = ||F_m||^2 + ||C_n||^2 - 2*F_m.C_n
// Block = 64 F-rows x 256-center half. A direct-to-registers (r9-proven).
// B LDS-staged in 32-center chunks, double-buffered, counted vmcnt(4).
// csq staged to LDS once (broadcast reads). Stores direct float4 (L2 merges,
// r2/r6-proven). 4 blocks/CU (33KB LDS, launch_bounds(256,4)), grid 1024,
// XCD-paired so both n-halves of an m-panel share one XCD's L2.
__global__ __launch_bounds__(256, 4) void dist_fused(
    const float* __restrict__ F, const unsigned short* __restrict__ Cbf,
    const float* __restrict__ csq, float* __restrict__ out, int M, int N) {
  __shared__ __align__(16) char Bs[2][32 * 512];   // 2 x 16 KB
  __shared__ __align__(16) float csq_s[256];       // this block's n-half

  const int t = threadIdx.x;
  const int w = t >> 6, l = t & 63;
  const int rl = l & 15, kh = l >> 4;
  const int amask = (rl & 7) << 4;    // B read-side XOR (LDS row%8 == rl%8)

  // XCD pairing: xcd = bid&7 owns works [xcd*128, xcd*128+128); work = m*2+nh
  // so both n-halves of an m-panel are adjacent on the SAME XCD (F L2-hot).
  const int workid = (blockIdx.x & 7) * 128 + (blockIdx.x >> 3);
  const int m0 = (workid >> 1) * 64;
  const int n0 = (workid & 1) * 256;
  const int mrow = m0 + w * 16 + rl;

  // B staging (per chunk 16KB = 4 rounds x 8 rows x 512B); source LINEAR
  // (Cbf pre-swizzled in memory), LDS dest linear = wave base + lane*16.
  const int srow = t >> 5;            // 0..7
  const int scol = (t & 31) * 16;     // 0..496
  const char* Bsrc = (const char*)Cbf + (size_t)(n0 + srow) * 512 + scol;
  // chunk advance: 32 rows * 512B = 16384; round advance: 8 rows = 4096.

#define STAGE(CH, BUF)                                                        \
  {                                                                           \
    _Pragma("unroll")                                                         \
    for (int j = 0; j < 4; ++j)                                               \
      gload16(Bsrc + (size_t)(CH) * 16384 + j * 4096,                         \
              (char*)Bs[BUF] + j * 4096 + t * 16);                            \
  }

  // prologue: chunk-0 staging + csq half (wave 0 only; whole-wave predicate)
  STAGE(0, 0)
  if (t < 64)
    gload16((const char*)csq + (size_t)n0 * 4 + t * 16, (char*)csq_s + t * 16);

  // A: 16 independent HBM loads straight to registers.
  const char* Arow = (const char*)F + (size_t)mrow * 1024 + kh * 32;
  f32x4 a0[8], a1[8];
#pragma unroll
  for (int kt = 0; kt < 8; ++kt) {
    a0[kt] = *reinterpret_cast<const f32x4*>(Arow + kt * 128);
    a1[kt] = *reinterpret_cast<const f32x4*>(Arow + kt * 128 + 16);
  }

  // fp32->bf16 fragments + exact row-norm partial; pin af against remat.
  bf16x8 af[8];
  float rsq = 0.f;
#pragma unroll
  for (int kt = 0; kt < 8; ++kt) {
    const f32x4 x = a0[kt], y = a1[kt];
    rsq += x[0] * x[0] + x[1] * x[1] + x[2] * x[2] + x[3] * x[3] +
           y[0] * y[0] + y[1] * y[1] + y[2] * y[2] + y[3] * y[3];
    bf16x8 v;
    v[0] = (short)f2bf(x[0]); v[1] = (short)f2bf(x[1]);
    v[2] = (short)f2bf(x[2]); v[3] = (short)f2bf(x[3]);
    v[4] = (short)f2bf(y[0]); v[5] = (short)f2bf(y[1]);
    v[6] = (short)f2bf(y[2]); v[7] = (short)f2bf(y[3]);
    af[kt] = v;
    asm volatile("" : "+v"(af[kt]));   // keep resident; block rematerialization
  }
  float fv = rsq;
  fv += __shfl_xor(fv, 16);
  fv += __shfl_xor(fv, 32);   // every lane: full ||F_row||^2

  asm volatile("s_waitcnt vmcnt(0)" ::: "memory");   // chunk 0 + csq landed
  __builtin_amdgcn_s_barrier();
  asm volatile("" ::: "memory");

#pragma unroll
  for (int c = 0; c < NCH; ++c) {
    const int cur = c & 1;
    if (c < NCH - 1) {
      STAGE(c + 1, cur ^ 1)
      // wait until only the 4 just-issued remain: drains chunk-c loads AND
      // last iteration's 2 stores (stores count in vmcnt).
      asm volatile("s_waitcnt vmcnt(4)" ::: "memory");
    } else {
      asm volatile("s_waitcnt vmcnt(0)" ::: "memory");
    }
    __builtin_amdgcn_s_barrier();    // chunk-c visible to all waves
    asm volatile("" ::: "memory");

#pragma unroll
    for (int ni = 0; ni < 2; ++ni) {
      f32x4 acc = (f32x4){0.f, 0.f, 0.f, 0.f};
#pragma unroll
      for (int kt = 0; kt < 8; ++kt) {
        const bf16x8 bfr = *reinterpret_cast<const bf16x8*>(
            (const char*)Bs[cur] + (ni * 16 + rl) * 512 + ((kt * 64 + kh * 16) ^ amask));
        // SWAPPED operands: D col = F-row (rl), D row = center (kh*4+reg). [r7-r10]
        acc = __builtin_amdgcn_mfma_f32_16x16x32_bf16(bfr, af[kt], acc, 0, 0, 0);
      }
      const int nloc = c * 32 + ni * 16 + kh * 4;
      const float4 cs4 = *reinterpret_cast<const float4*>(
          (const char*)csq_s + (size_t)nloc * 4);   // same addr across rl: broadcast
      float4 v;
      v.x = fv + cs4.x - 2.0f * acc[0];
      v.y = fv + cs4.y - 2.0f * acc[1];
      v.z = fv + cs4.z - 2.0f * acc[2];
      v.w = fv + cs4.w - 2.0f * acc[3];
      *reinterpret_cast<float4*>(&out[(size_t)mrow * N + n0 + nloc]) = v;
    }

    __builtin_amdgcn_s_barrier();    // all reads of Bs[cur] done before restage
    asm volatile("" ::: "memory");
  }
}

extern "C" void kernel_launch(void* const* d_in, const int* in_sizes, int n_in,
                              void* d_out, int out_size, void* d_ws, size_t ws_size,
                              hipStream_t stream) {
  const float* F = (const float*)d_in[0];   // (16, 2048, 256) fp32
  const float* C = (const float*)d_in[1];   // (1, 512, 256) fp32
  float* out = (float*)d_out;               // (16, 2048, 512) fp32
  const int D = 256;
  const int M = in_sizes[0] / D;            // 32768
  const int N = in_sizes[1] / D;            // 512

  unsigned short* Cbf = (unsigned short*)d_ws;    // N*256 bf16 (128B-block swizzled)
  float* csq = (float*)(Cbf + (size_t)N * D);     // N fp32

  hipLaunchKernelGGL(prep_c, dim3(N / 4), dim3(256), 0, stream, C, Cbf, csq, N);
  const int nwg = (M / 64) * 2;                   // 1024, divisible by 8
  hipLaunchKernelGGL(dist_fused, dim3(nwg), dim3(256), 0, stream,
                     F, Cbf, csq, out, M, N);
}